// Round 4
// baseline (2145.001 us; speedup 1.0000x reference)
//
#include <hip/hip_runtime.h>
#include <math.h>

// FISTA, phase-split 4x, XCD-colocated, L3-atomic exchange — R21.
// R20 post-mortem: (1) per-thread direct L3 loads in stage 2 (486x12 agent
// atomics, uncached) tripled fabric traffic (FETCH 35->231 MB) — the shared
// pre-pass exists to read each partial ONCE; restored. (2) VGPR stuck at 128
// (compiler default cap) -> spills; fixed with __launch_bounds__(512,1).
// (3) Recurring ~32ms outlier dispatches track 2-blocks/CU packing; LDS
// padded >80 KB forces 1 block/CU (256 blocks = 256 CUs, exact).
// Kept from R18/R20 (compute wins): 512 thr / 8 waves, 2/SIMD balanced
// (wave 0 does both 3-tap boundary rows 0+8); 75 conv weights in VGPRs;
// Wct (24), y_last (8), x (3) in registers; float4 stage-2 LDS ops; DPP
// butterfly reduction (R20's LDS-transpose cost the same issue and raised
// bank conflicts).
// Exchange (R17-proven, measured 1365): stage1 -> sync (drains vmcnt; Ap
// atomic stores acked at L3) -> tid0 relaxed fetch_add + relaxed spin
// (target 4*(iter+1)) -> sync -> pre-pass (tid<243: 4 relaxed atomic loads,
// +b_conv, -> LDS) -> sync -> stage2 -> sync.
// WAR audit: pre-pass(k) < end-barrier(k) < stage1(k+1) < add(k+1);
// spin(k+1) sees 4(k+2) => all blocks did pre-pass(k); only then stage1(k+2)
// rewrites buffer k&1.
//
// Phase decomposition (proven R2-R20): a[cell,co] = sum_{d(5x5),ci,p}
// y[cell+d,ci,p] W[d,ci,p,co]; block g sums its 16 phases -> partial a.
// Wave = output row; lane = (q=ci quadrant, p_local); q=3 lanes carry zero
// weights (y reads duplicate q=2: same-address broadcast, free).

#define ITERS 200
#define THREADS 512
// d_ws float offsets
#define WGOFF 0          // 19200: [g][t*3+co][lane], q=3 lanes zeroed
#define WCTOFF 19200     // 576: [c][ci][p]
#define APOFF 19776      // 2 * 64 * 4 * 243 = 124416 (double-buffered)
#define CNTOFF 144192    // int offsets: 64 images x 64-int padding
// LDS float offsets
#define LY 0             // y: 3888 = 243 idx3 x 16 p_local
#define LA 3888          // a: 243 (+1 pad)
#define SMEMF 20608      // 82,432 B: > 80 KB -> exactly 1 block/CU

template <int CTRL>
__device__ __forceinline__ float dpp_add(float x) {
  int moved = __builtin_amdgcn_update_dpp(0, __float_as_int(x), CTRL, 0xF, 0xF, true);
  return x + __int_as_float(moved);
}
// gfx9 wave64 sum -> lane 63. Proven R2-R20.
__device__ __forceinline__ float wave_sum64_to_lane63(float x) {
  x = dpp_add<0x111>(x);
  x = dpp_add<0x112>(x);
  x = dpp_add<0x114>(x);
  x = dpp_add<0x118>(x);
  x = dpp_add<0x142>(x);
  x = dpp_add<0x143>(x);
  return x;
}

// WG[((g*75 + t*3 + co))*64 + lane] = w_conv[8*th+ph][8*tw+pw][ci=q][co]
//   with lane=(q,pl), p = g*16+pl; q==3 -> 0 (dead quadrant).
// WCT2[c*192 + ci*64 + p] = (rh<5 && rw<5) ? w_ct[4-rh][4-rw][ci][c] : 0,
//   p = rh*8+rw.
__global__ void k0_init(const float* __restrict__ w_conv,
                        const float* __restrict__ w_ct,
                        float* __restrict__ ws) {
  const int i = blockIdx.x * 256 + threadIdx.x;
  if (i < 19200) {
    const int lane = i & 63;
    const int rest = i >> 6;          // g*75 + t*3 + co
    const int g = rest / 75;
    const int tc = rest - 75 * g;
    const int t = tc / 3;
    const int co = tc - 3 * t;
    const int th = t / 5;
    const int tw = t - 5 * th;
    const int q = lane >> 4;
    const int pl = lane & 15;
    float v = 0.f;
    if (q < 3) {
      const int p = g * 16 + pl;
      const int ph = p >> 3;
      const int pw = p & 7;
      v = w_conv[(((8 * th + ph) * 40 + (8 * tw + pw)) * 3 + q) * 3 + co];
    }
    ws[WGOFF + i] = v;
  }
  if (i < 576) {
    const int p = i & 63;
    const int ci = (i >> 6) % 3;
    const int c = i / 192;
    const int rh = p >> 3;
    const int rw = p & 7;
    float v = 0.f;
    if (rh < 5 && rw < 5) v = w_ct[(((4 - rh) * 5 + (4 - rw)) * 3 + ci) * 3 + c];
    ws[WCTOFF + i] = v;
  }
  if (i < 4096) ((int*)ws)[CNTOFF + i] = 0;
}

__global__ __launch_bounds__(THREADS, 1) void fista_split(
    float* __restrict__ ws,
    const float* __restrict__ x, const float* __restrict__ lam,
    const float* __restrict__ b_conv, const float* __restrict__ b_ct,
    float* __restrict__ out) {
  __shared__ __align__(16) float smem[SMEMF];
  const int tid = threadIdx.x;
  const int blk = blockIdx.x;
  const int n = blk & 63;         // image  (XCD colocation: n, n+64, n+128,
  const int g = blk >> 6;         //  n+192 share blk%8)
  const int lane = tid & 63;
  const int wid = tid >> 6;       // wave index, 8 waves
  const int q = lane >> 4;        // ci quadrant (3 = dead)
  const int pl = lane & 15;
  const int ylane = ((q < 3) ? q : 2) * 16 + pl;  // q=3 dupes q=2: broadcast
  // Waves 1-7 -> rows {2,4,6,1,3,5,7}; wave 0 -> rows 0 AND 8 (both 3-tap).
  const int row0 = (wid & 3) * 2 + (wid >> 2);
  const int npass = (wid == 0) ? 2 : 1;

  int* __restrict__ cnt = (int*)ws + CNTOFF + n * 64;
  const float lam_n = lam[n];
  const float bcv = b_conv[tid % 3];   // pre-pass bias (used when tid<243)

  // ---- conv weights -> 75 VGPRs (iteration-invariant) ----
  float wreg[75];
#pragma unroll
  for (int i = 0; i < 75; ++i) wreg[i] = ws[WGOFF + g * 4800 + i * 64 + lane];

  // ---- stage-2 per-thread constants: thread t<486 owns y elements
  // e = 8t .. 8t+7  (idx3 = t>>1, pl-half = t&1); y_last lives in regs ----
  const int idx3 = tid >> 1;
  const int cell = idx3 / 3;
  const int c = idx3 - 3 * cell;
  const int cb = 3 * cell;
  const int pbase = g * 16 + (tid & 1) * 8;
  float wct[3][8];
  float yl[8];
#pragma unroll
  for (int j = 0; j < 8; ++j) yl[j] = 0.f;
  float xr0 = 0.f, xr1 = 0.f, xr2 = 0.f, bctc = 0.f;
  if (tid < 486) {
#pragma unroll
    for (int ci = 0; ci < 3; ++ci)
#pragma unroll
      for (int j = 0; j < 8; ++j)
        wct[ci][j] = ws[WCTOFF + c * 192 + ci * 64 + pbase + j];
    bctc = b_ct[c];
    xr0 = x[n * 243 + cb + 0];
    xr1 = x[n * 243 + cb + 1];
    xr2 = x[n * 243 + cb + 2];
  }

  // ---- stage LDS: zero y ----
  for (int i = tid; i < 3888; i += THREADS) smem[LY + i] = 0.f;
  __syncthreads();

  float t = 1.0f;
#pragma unroll 1
  for (int iter = 0; iter < ITERS; ++iter) {
    // ===== stage 1: partial a over this block's 16 phases =====
#pragma unroll 1
    for (int pass = 0; pass < npass; ++pass) {
      const int oh = pass ? 8 : row0;
      float acc[27];               // [ow*3 + co]
#pragma unroll
      for (int k = 0; k < 27; ++k) acc[k] = 0.f;

#pragma unroll
      for (int th = 0; th < 5; ++th) {
        const int r = oh + th - 2;          // input row
        if (r >= 0 && r <= 8) {
          float rv[13];                     // y col (k-2), zero-padded
          rv[0] = 0.f; rv[1] = 0.f; rv[11] = 0.f; rv[12] = 0.f;
#pragma unroll
          for (int wc = 0; wc < 9; ++wc)
            rv[wc + 2] = smem[LY + r * 432 + wc * 48 + ylane];

#pragma unroll
          for (int tw = 0; tw < 5; ++tw) {
            const int tb = (th * 5 + tw) * 3;
            const float w0 = wreg[tb + 0];
            const float w1 = wreg[tb + 1];
            const float w2 = wreg[tb + 2];
#pragma unroll
            for (int ow = 0; ow < 9; ++ow) {
              const float y = rv[ow + tw];
              acc[ow * 3 + 0] += y * w0;
              acc[ow * 3 + 1] += y * w1;
              acc[ow * 3 + 2] += y * w2;
            }
          }
        }
      }

#pragma unroll
      for (int k = 0; k < 27; ++k) acc[k] = wave_sum64_to_lane63(acc[k]);
      if (lane == 63) {
        float* ap = ws + APOFF + ((((iter & 1) * 64 + n) * 4 + g) * 243) + oh * 27;
#pragma unroll
        for (int k = 0; k < 27; ++k)
          __hip_atomic_store(ap + k, acc[k], __ATOMIC_RELAXED,
                             __HIP_MEMORY_SCOPE_AGENT);
      }
    }

    // ===== centralized barrier (R17-proven): one spinner, rest at s_barrier ==
    __syncthreads();               // drains vmcnt: Ap stores acked at L3
    if (tid == 0) {
      __hip_atomic_fetch_add(cnt, 1, __ATOMIC_RELAXED, __HIP_MEMORY_SCOPE_AGENT);
      const int target = 4 * (iter + 1);
      while (__hip_atomic_load(cnt, __ATOMIC_RELAXED, __HIP_MEMORY_SCOPE_AGENT)
             < target)
        __builtin_amdgcn_s_sleep(1);
    }
    __syncthreads();

    // ===== pre-pass: a = sum_g Ap + b_conv -> LDS (atomic loads: L3-fresh) ====
    if (tid < 243) {
      const float* ap = ws + APOFF + ((iter & 1) * 64 + n) * 972;
      const float a0 = __hip_atomic_load(ap + tid, __ATOMIC_RELAXED,
                                         __HIP_MEMORY_SCOPE_AGENT);
      const float a1 = __hip_atomic_load(ap + 243 + tid, __ATOMIC_RELAXED,
                                         __HIP_MEMORY_SCOPE_AGENT);
      const float a2 = __hip_atomic_load(ap + 486 + tid, __ATOMIC_RELAXED,
                                         __HIP_MEMORY_SCOPE_AGENT);
      const float a3 = __hip_atomic_load(ap + 729 + tid, __ATOMIC_RELAXED,
                                         __HIP_MEMORY_SCOPE_AGENT);
      smem[LA + tid] = a0 + a1 + a2 + a3 + bcv;
    }
    __syncthreads();

    const float tn = (1.0f + sqrtf(1.0f + 4.0f * t * t)) * 0.5f;
    const float beta = (t - 1.0f) / tn;    // beta_0 = 0
    t = tn;

    // ===== stage 2: 8 consecutive elements per thread, vectorized =====
    const bool lastit = (iter == ITERS - 1);
    if (tid < 486) {
      const float a0 = smem[LA + cb + 0];
      const float a1 = smem[LA + cb + 1];
      const float a2 = smem[LA + cb + 2];
      const float r0 = xr0 - a0;
      const float r1 = xr1 - a1;
      const float r2 = xr2 - a2;

      float4* lyv = (float4*)&smem[LY];
      const float4 y0 = lyv[2 * tid];
      const float4 y1 = lyv[2 * tid + 1];
      const float yv[8] = {y0.x, y0.y, y0.z, y0.w, y1.x, y1.y, y1.z, y1.w};
      float yn[8];
#pragma unroll
      for (int j = 0; j < 8; ++j) {
        const float re = bctc + r0 * wct[0][j] + r1 * wct[1][j] + r2 * wct[2][j];
        const float wvv = yv[j] - re;
        yn[j] = fmaxf(wvv - lam_n, 0.f) - fmaxf(-wvv - lam_n, 0.f);
      }

      if (!lastit) {
        float4 m0, m1;
        m0.x = yn[0] + beta * (yn[0] - yl[0]);
        m0.y = yn[1] + beta * (yn[1] - yl[1]);
        m0.z = yn[2] + beta * (yn[2] - yl[2]);
        m0.w = yn[3] + beta * (yn[3] - yl[3]);
        m1.x = yn[4] + beta * (yn[4] - yl[4]);
        m1.y = yn[5] + beta * (yn[5] - yl[5]);
        m1.z = yn[6] + beta * (yn[6] - yl[6]);
        m1.w = yn[7] + beta * (yn[7] - yl[7]);
#pragma unroll
        for (int j = 0; j < 8; ++j) yl[j] = yn[j];
        lyv[2 * tid] = m0; lyv[2 * tid + 1] = m1;
      } else {
        const int part = pbase >> 3;       // p>>3 constant over j
        const int qh = cell / 9;
        const int qw = cell - 9 * qh;
        const int ih = 8 * qh + part;
        float* op = out + ((n * 72 + ih) * 72 + 8 * qw) * 3 + c;
#pragma unroll
        for (int j = 0; j < 8; ++j) op[3 * j] = yn[j];
      }
    }
    __syncthreads();
  }
}

extern "C" void kernel_launch(void* const* d_in, const int* in_sizes, int n_in,
                              void* d_out, int out_size, void* d_ws, size_t ws_size,
                              hipStream_t stream) {
  const float* x      = (const float*)d_in[0];
  const float* lam    = (const float*)d_in[1];
  const float* w_conv = (const float*)d_in[2];
  const float* b_conv = (const float*)d_in[3];
  const float* w_ct   = (const float*)d_in[4];
  const float* b_ct   = (const float*)d_in[5];
  float* out = (float*)d_out;
  float* ws  = (float*)d_ws;  // needs ~593 KB (unchanged)

  hipLaunchKernelGGL(k0_init, dim3(80), dim3(256), 0, stream, w_conv, w_ct, ws);
  hipLaunchKernelGGL(fista_split, dim3(256), dim3(THREADS), 0, stream,
                     ws, x, lam, b_conv, b_ct, out);
}

// Round 5
// 1242.650 us; speedup vs baseline: 1.7262x; 1.7262x over previous
//
#include <hip/hip_runtime.h>
#include <math.h>

// FISTA, phase-split 4x, XCD-colocated, L3-atomic exchange — R22.
// R18-R21 post-mortem: every register-hoist variant pinned VGPR at the
// compiler's 128 cap -> per-iteration scratch spill/reload of the
// loop-carried set (wct/yl/xr). WRITE_SIZE tracked it: 394 MB (R17, 48
// VGPR) -> 410 -> 907 -> 1326 MB (R21). Also, re-derived issue math:
// max-SIMD stage-1 slots are 2802 in BOTH the 576-thr and "rebalanced"
// 512-thr layouts (the 351-slot DPP+store block per pass dominates), so
// the rebalance never paid. R22 = R17's proven structure (576 thr, 9
// waves = 9 rows, all state in LDS, 48-VGPR regime, 4-sync centralized
// exchange) plus two pressure-neutral cuts:
//  1. LDS weights relaid [tap][lane][4co] -> ONE ds_read_b128 per (th,tw)
//     (was 3x ds_read_b32): -10 issue slots/tap-row, canonical stride-16B
//     conflict-free pattern. One-time init scatter; ws layout unchanged.
//  2. Stage 2: threads 0..485 own 8 consecutive y elems; y/y_last as
//     float4 LDS ops (8 b128 replace ~54 b32 per thread). a/x/Wct stay
//     scalar-in-LDS exactly as R17 -> no loop-carried registers added.
// Exchange (R17-proven): stage1 -> sync (drains vmcnt; Ap atomic stores
// acked at L3) -> tid0 relaxed fetch_add + relaxed spin (target
// 4*(iter+1)) -> sync -> pre-pass (tid<243: 4 relaxed atomic loads,
// +b_conv -> LDS) -> sync -> stage2 -> sync.
// WAR audit: pre-pass(k) < end-barrier(k) < stage1(k+1) < add(k+1);
// spin(k+1) sees 4(k+2) => all blocks did pre-pass(k); only then
// stage1(k+2) rewrites buffer k&1.
//
// Phase decomposition (proven R2-R21): a[cell,co] = sum_{d(5x5),ci,p}
// y[cell+d,ci,p] W[d,ci,p,co]; block g sums its 16 phases -> partial a.
// Wave = output row; lane = (q=ci quadrant, p_local); q=3 lanes carry zero
// weights (y reads duplicate q=2: same-address broadcast, free).

#define ITERS 200
#define THREADS 576
// d_ws float offsets (EXACTLY R17's layout: ~593 KB, proven to fit)
#define WGOFF 0          // 19200: [g][t*3+co][lane], q=3 lanes zeroed
#define WCTOFF 19200     // 576: [(p*3+c)*3+ci]
#define APOFF 19776      // 2 * 64 * 4 * 243 = 124416 (double-buffered)
#define CNTOFF 144192    // int offsets: 64 images x 64-int padding
// LDS float offsets
#define LY 0             // y: 3888 = 243 idx3 x 16 p_local (16B-aligned)
#define LYL 3888         // y_last: 3888 (byte 15552, 16B-aligned)
#define LA 7776          // a: 243 (+1 pad)
#define LXS 8020         // x image slice: 243 (+pad to align LWG)
#define LWG 8264         // weights g-slice: 25 taps x 64 lanes x 4 (co,pad)
#define LWCT 14664       // Wct: 576
#define SMEMF 15240      // 60,960 B

template <int CTRL>
__device__ __forceinline__ float dpp_add(float x) {
  int moved = __builtin_amdgcn_update_dpp(0, __float_as_int(x), CTRL, 0xF, 0xF, true);
  return x + __int_as_float(moved);
}
// gfx9 wave64 sum -> lane 63. Proven R2-R21.
__device__ __forceinline__ float wave_sum64_to_lane63(float x) {
  x = dpp_add<0x111>(x);
  x = dpp_add<0x112>(x);
  x = dpp_add<0x114>(x);
  x = dpp_add<0x118>(x);
  x = dpp_add<0x142>(x);
  x = dpp_add<0x143>(x);
  return x;
}

// WG[((g*75 + t*3 + co))*64 + lane] = w_conv[8*th+ph][8*tw+pw][ci=q][co]
//   with lane=(q,pl), p = g*16+pl; q==3 -> 0 (dead quadrant).
// Wct[((rh*8+rw)*3+c)*3 + ci] = (rh<5 && rw<5) ? w_ct[4-rh][4-rw][ci][c] : 0.
// (k0_init verbatim R17 — ws layout/size unchanged.)
__global__ void k0_init(const float* __restrict__ w_conv,
                        const float* __restrict__ w_ct,
                        float* __restrict__ ws) {
  const int i = blockIdx.x * 256 + threadIdx.x;
  if (i < 19200) {
    const int lane = i & 63;
    const int rest = i >> 6;          // g*75 + t*3 + co
    const int g = rest / 75;
    const int tc = rest - 75 * g;
    const int t = tc / 3;
    const int co = tc - 3 * t;
    const int th = t / 5;
    const int tw = t - 5 * th;
    const int q = lane >> 4;
    const int pl = lane & 15;
    float v = 0.f;
    if (q < 3) {
      const int p = g * 16 + pl;
      const int ph = p >> 3;
      const int pw = p & 7;
      v = w_conv[(((8 * th + ph) * 40 + (8 * tw + pw)) * 3 + q) * 3 + co];
    }
    ws[WGOFF + i] = v;
  }
  if (i < 576) {
    const int ci = i % 3;
    const int r1 = i / 3;
    const int c = r1 % 3;
    const int r2 = r1 / 3;
    const int rw = r2 % 8;
    const int rh = r2 / 8;
    float v = 0.f;
    if (rh < 5 && rw < 5) v = w_ct[(((4 - rh) * 5 + (4 - rw)) * 3 + ci) * 3 + c];
    ws[WCTOFF + i] = v;
  }
  if (i < 4096) ((int*)ws)[CNTOFF + i] = 0;
}

__global__ __launch_bounds__(THREADS) void fista_split(
    float* __restrict__ ws,
    const float* __restrict__ x, const float* __restrict__ lam,
    const float* __restrict__ b_conv, const float* __restrict__ b_ct,
    float* __restrict__ out) {
  __shared__ __align__(16) float smem[SMEMF];
  const int tid = threadIdx.x;
  const int blk = blockIdx.x;
  const int n = blk & 63;         // image  (XCD colocation: n, n+64, n+128,
  const int g = blk >> 6;         //  n+192 share blk%8)
  const int lane = tid & 63;
  const int oh = tid >> 6;        // wave index == output row (9 waves, 9 rows)
  const int q = lane >> 4;        // ci quadrant (3 = dead)
  const int pl = lane & 15;
  const int ylane = ((q < 3) ? q : 2) * 16 + pl;  // q=3 dupes q=2: broadcast

  int* __restrict__ cnt = (int*)ws + CNTOFF + n * 64;
  const float lam_n = lam[n];
  const float bcv = b_conv[tid % 3];   // pre-pass bias (used when tid<243)
  const float bct0 = b_ct[0], bct1 = b_ct[1], bct2 = b_ct[2];

  // ---- stage LDS ----
  // zero everything (incl. LWG pad slots), then scatter weights into the
  // [tap][lane][4] layout (one-time; race-free via the middle sync).
  for (int i = tid; i < SMEMF; i += THREADS) smem[i] = 0.f;
  __syncthreads();
  for (int i = tid; i < 4800; i += THREADS) {
    const int lane_i = i & 63;
    const int tc = i >> 6;            // t*3 + co
    const int t_i = tc / 3;
    const int co_i = tc - 3 * t_i;
    smem[LWG + (t_i * 64 + lane_i) * 4 + co_i] = ws[WGOFF + g * 4800 + i];
  }
  smem[LWCT + tid] = ws[WCTOFF + tid];
  if (tid < 243) smem[LXS + tid] = x[n * 243 + tid];
  __syncthreads();

  // stage-2 ownership: thread t<486 owns elements e = 8t .. 8t+7
  // (idx3 = t>>1, p_local-half = t&1). Same per-element math as R17.
  const int idx3 = tid >> 1;
  const int cell = idx3 / 3;
  const int c = idx3 - 3 * cell;
  const int cb = 3 * cell;
  const int plb = (tid & 1) * 8;       // p_local base (0 or 8)

  float t = 1.0f;
#pragma unroll 1
  for (int iter = 0; iter < ITERS; ++iter) {
    // ===== stage 1: partial a over this block's 16 phases; wave = oh ==========
    {
      float acc[27];               // [ow*3 + co]
#pragma unroll
      for (int k = 0; k < 27; ++k) acc[k] = 0.f;

#pragma unroll
      for (int th = 0; th < 5; ++th) {
        const int r = oh + th - 2;          // input row
        if (r >= 0 && r <= 8) {
          float rv[13];                     // y col (k-2), zero-padded
          rv[0] = 0.f; rv[1] = 0.f; rv[11] = 0.f; rv[12] = 0.f;
#pragma unroll
          for (int wc = 0; wc < 9; ++wc)
            rv[wc + 2] = smem[LY + r * 432 + wc * 48 + ylane];

#pragma unroll
          for (int tw = 0; tw < 5; ++tw) {
            // one ds_read_b128 fetches w0,w1,w2 (+pad) for this (th,tw)
            const float4 wv =
                *(const float4*)&smem[LWG + ((th * 5 + tw) * 64 + lane) * 4];
            const float w0 = wv.x;
            const float w1 = wv.y;
            const float w2 = wv.z;
#pragma unroll
            for (int ow = 0; ow < 9; ++ow) {
              const float y = rv[ow + tw];
              acc[ow * 3 + 0] += y * w0;
              acc[ow * 3 + 1] += y * w1;
              acc[ow * 3 + 2] += y * w2;
            }
          }
        }
      }

#pragma unroll
      for (int k = 0; k < 27; ++k) acc[k] = wave_sum64_to_lane63(acc[k]);
      if (lane == 63) {
        float* ap = ws + APOFF + ((((iter & 1) * 64 + n) * 4 + g) * 243) + oh * 27;
#pragma unroll
        for (int k = 0; k < 27; ++k)
          __hip_atomic_store(ap + k, acc[k], __ATOMIC_RELAXED,
                             __HIP_MEMORY_SCOPE_AGENT);
      }
    }

    // ===== centralized barrier (R17-proven): one spinner, rest at s_barrier ==
    __syncthreads();               // compiler drains vmcnt: Ap stores acked at L3
    if (tid == 0) {
      __hip_atomic_fetch_add(cnt, 1, __ATOMIC_RELAXED, __HIP_MEMORY_SCOPE_AGENT);
      const int target = 4 * (iter + 1);
      while (__hip_atomic_load(cnt, __ATOMIC_RELAXED, __HIP_MEMORY_SCOPE_AGENT)
             < target)
        __builtin_amdgcn_s_sleep(1);
    }
    __syncthreads();

    // ===== pre-pass: a = sum_g Ap + b_conv -> LDS (atomic loads: L3-fresh) ====
    if (tid < 243) {
      const float* ap = ws + APOFF + ((iter & 1) * 64 + n) * 972;
      const float a0 = __hip_atomic_load(ap + tid, __ATOMIC_RELAXED,
                                         __HIP_MEMORY_SCOPE_AGENT);
      const float a1 = __hip_atomic_load(ap + 243 + tid, __ATOMIC_RELAXED,
                                         __HIP_MEMORY_SCOPE_AGENT);
      const float a2 = __hip_atomic_load(ap + 486 + tid, __ATOMIC_RELAXED,
                                         __HIP_MEMORY_SCOPE_AGENT);
      const float a3 = __hip_atomic_load(ap + 729 + tid, __ATOMIC_RELAXED,
                                         __HIP_MEMORY_SCOPE_AGENT);
      smem[LA + tid] = a0 + a1 + a2 + a3 + bcv;
    }
    __syncthreads();

    const float tn = (1.0f + sqrtf(1.0f + 4.0f * t * t)) * 0.5f;
    const float beta = (t - 1.0f) / tn;    // beta_0 = 0
    t = tn;

    // ===== stage 2: 8 consecutive elements per thread; y/y_last as float4;
    // a/x/Wct scalar from LDS (no loop-carried registers added) =====
    const bool lastit = (iter == ITERS - 1);
    if (tid < 486) {
      const float a0 = smem[LA + cb + 0];
      const float a1 = smem[LA + cb + 1];
      const float a2 = smem[LA + cb + 2];
      const float r0 = smem[LXS + cb + 0] - a0;
      const float r1 = smem[LXS + cb + 1] - a1;
      const float r2v = smem[LXS + cb + 2] - a2;
      const float bct = (c == 0) ? bct0 : ((c == 1) ? bct1 : bct2);

      float4* lyv  = (float4*)&smem[LY];
      float4* lylv = (float4*)&smem[LYL];
      const float4 y0 = lyv[2 * tid];
      const float4 y1 = lyv[2 * tid + 1];
      const float yv[8] = {y0.x, y0.y, y0.z, y0.w, y1.x, y1.y, y1.z, y1.w};
      float yn[8];
#pragma unroll
      for (int j = 0; j < 8; ++j) {
        const int p = g * 16 + plb + j;
        const float* wp = &smem[LWCT + (p * 3 + c) * 3];
        const float re = bct + r0 * wp[0] + r1 * wp[1] + r2v * wp[2];
        const float wvv = yv[j] - re;
        yn[j] = fmaxf(wvv - lam_n, 0.f) - fmaxf(-wvv - lam_n, 0.f);
      }

      if (!lastit) {
        const float4 l0 = lylv[2 * tid];
        const float4 l1 = lylv[2 * tid + 1];
        const float ylv[8] = {l0.x, l0.y, l0.z, l0.w, l1.x, l1.y, l1.z, l1.w};
        float4 s0, s1, m0, m1;
        s0.x = yn[0]; s0.y = yn[1]; s0.z = yn[2]; s0.w = yn[3];
        s1.x = yn[4]; s1.y = yn[5]; s1.z = yn[6]; s1.w = yn[7];
        m0.x = yn[0] + beta * (yn[0] - ylv[0]);
        m0.y = yn[1] + beta * (yn[1] - ylv[1]);
        m0.z = yn[2] + beta * (yn[2] - ylv[2]);
        m0.w = yn[3] + beta * (yn[3] - ylv[3]);
        m1.x = yn[4] + beta * (yn[4] - ylv[4]);
        m1.y = yn[5] + beta * (yn[5] - ylv[5]);
        m1.z = yn[6] + beta * (yn[6] - ylv[6]);
        m1.w = yn[7] + beta * (yn[7] - ylv[7]);
        lylv[2 * tid] = s0; lylv[2 * tid + 1] = s1;
        lyv[2 * tid]  = m0; lyv[2 * tid + 1]  = m1;
      } else {
        const int part = (g * 16 + plb) >> 3;   // p>>3 constant over j
        const int qh = cell / 9;
        const int qw = cell - 9 * qh;
        const int ih = 8 * qh + part;
        float* op = out + ((n * 72 + ih) * 72 + 8 * qw) * 3 + c;
#pragma unroll
        for (int j = 0; j < 8; ++j) op[3 * j] = yn[j];
      }
    }
    __syncthreads();
  }
}

extern "C" void kernel_launch(void* const* d_in, const int* in_sizes, int n_in,
                              void* d_out, int out_size, void* d_ws, size_t ws_size,
                              hipStream_t stream) {
  const float* x      = (const float*)d_in[0];
  const float* lam    = (const float*)d_in[1];
  const float* w_conv = (const float*)d_in[2];
  const float* b_conv = (const float*)d_in[3];
  const float* w_ct   = (const float*)d_in[4];
  const float* b_ct   = (const float*)d_in[5];
  float* out = (float*)d_out;
  float* ws  = (float*)d_ws;  // needs ~593 KB (R17 layout, unchanged)

  hipLaunchKernelGGL(k0_init, dim3(80), dim3(256), 0, stream, w_conv, w_ct, ws);
  hipLaunchKernelGGL(fista_split, dim3(256), dim3(THREADS), 0, stream,
                     ws, x, lam, b_conv, b_ct, out);
}

// Round 6
// 992.403 us; speedup vs baseline: 2.1614x; 1.2522x over previous
//
#include <hip/hip_runtime.h>
#include <math.h>

// FISTA, phase-split 4x, XCD-colocated, L3-atomic exchange — R23.
// R22 measured 1242 us (best). Counter arithmetic closed: WRITE_SIZE
// 1971 KB/iter == 256blk x 9waves x 27 single-lane atomic dword stores
// x 32B sector -> lane63's serial stores are 62K fabric ops/iter. The
// coalesced pre-pass loads cost only 133 KB/iter (proof coalescing works
// for agent atomics). R23 changes (structure otherwise R22-identical):
//  1. Reduction: 6-stage DPP butterfly (324 VALU/wave-pass) -> 2 DPP
//     stages (4-lane group sums) + LDS transpose (16 partials/row, 27
//     rows, stride 20 = conflict-free) + lanes<27 final sum (4x b128 +
//     15 adds) + ONE coalesced 27-lane atomic store (was 27 serial).
//     ~130 VALU/pass, 27x fewer fabric store ops.
//  2. Compile-time trim of structural-zero fmacs (col=ow+tw-2 outside
//     [0,8]): 135 -> 117 fmacs/tap-row (-13%).
//  3. Wave->row perm {0,4,2,3,8,5,6,7,1}: SIMD0 (wid 0,4,8) carries rows
//     {0,8,1} = 10 tap-row units (was 11). Harmless if wid%4 != SIMD.
// Exchange (R17/R22-proven): stage1 -> sync (drains vmcnt; stores acked
// at L3) -> tid0 relaxed fetch_add + relaxed spin (target 4*(iter+1)) ->
// sync -> pre-pass (tid<243: 4 relaxed atomic loads +b_conv -> LDS) ->
// sync -> stage2 -> sync.
// WAR audit: pre-pass(k) < end-barrier(k) < stage1(k+1) < add(k+1);
// spin(k+1) sees 4(k+2) => all blocks did pre-pass(k); only then
// stage1(k+2) rewrites buffer k&1. Transpose scratch is per-wave private,
// reused only next iteration (own lgkmcnt(0) + barrier chain orders it).
//
// Phase decomposition (proven R2-R22): a[cell,co] = sum_{d(5x5),ci,p}
// y[cell+d,ci,p] W[d,ci,p,co]; block g sums its 16 phases -> partial a.
// Wave = output row; lane = (q=ci quadrant, p_local); q=3 lanes carry zero
// weights (y reads duplicate q=2: same-address broadcast, free).

#define ITERS 200
#define THREADS 576
// d_ws float offsets (EXACTLY R17/R22's layout: ~593 KB)
#define WGOFF 0          // 19200: [g][t*3+co][lane], q=3 lanes zeroed
#define WCTOFF 19200     // 576: [(p*3+c)*3+ci]
#define APOFF 19776      // 2 * 64 * 4 * 243 = 124416 (double-buffered)
#define CNTOFF 144192    // int offsets: 64 images x 64-int padding
// LDS float offsets
#define LY 0             // y: 3888 = 243 idx3 x 16 p_local (16B-aligned)
#define LYL 3888         // y_last: 3888
#define LA 7776          // a: 243 (+1 pad)
#define LXS 8020         // x image slice: 243 (+pad)
#define LWG 8264         // weights g-slice: 25 taps x 64 lanes x 4
#define LWCT 14664       // Wct: 576
#define LT 15240         // transpose scratch: 9 waves x 27 rows x stride 20
#define SMEMF 20100      // 80,400 B (1 block/CU)

template <int CTRL>
__device__ __forceinline__ float dpp_add(float x) {
  int moved = __builtin_amdgcn_update_dpp(0, __float_as_int(x), CTRL, 0xF, 0xF, true);
  return x + __int_as_float(moved);
}

// WG[((g*75 + t*3 + co))*64 + lane] = w_conv[8*th+ph][8*tw+pw][ci=q][co]
//   with lane=(q,pl), p = g*16+pl; q==3 -> 0 (dead quadrant).
// Wct[((rh*8+rw)*3+c)*3 + ci] = (rh<5 && rw<5) ? w_ct[4-rh][4-rw][ci][c] : 0.
__global__ void k0_init(const float* __restrict__ w_conv,
                        const float* __restrict__ w_ct,
                        float* __restrict__ ws) {
  const int i = blockIdx.x * 256 + threadIdx.x;
  if (i < 19200) {
    const int lane = i & 63;
    const int rest = i >> 6;          // g*75 + t*3 + co
    const int g = rest / 75;
    const int tc = rest - 75 * g;
    const int t = tc / 3;
    const int co = tc - 3 * t;
    const int th = t / 5;
    const int tw = t - 5 * th;
    const int q = lane >> 4;
    const int pl = lane & 15;
    float v = 0.f;
    if (q < 3) {
      const int p = g * 16 + pl;
      const int ph = p >> 3;
      const int pw = p & 7;
      v = w_conv[(((8 * th + ph) * 40 + (8 * tw + pw)) * 3 + q) * 3 + co];
    }
    ws[WGOFF + i] = v;
  }
  if (i < 576) {
    const int ci = i % 3;
    const int r1 = i / 3;
    const int c = r1 % 3;
    const int r2 = r1 / 3;
    const int rw = r2 % 8;
    const int rh = r2 / 8;
    float v = 0.f;
    if (rh < 5 && rw < 5) v = w_ct[(((4 - rh) * 5 + (4 - rw)) * 3 + ci) * 3 + c];
    ws[WCTOFF + i] = v;
  }
  if (i < 4096) ((int*)ws)[CNTOFF + i] = 0;
}

__global__ __launch_bounds__(THREADS) void fista_split(
    float* __restrict__ ws,
    const float* __restrict__ x, const float* __restrict__ lam,
    const float* __restrict__ b_conv, const float* __restrict__ b_ct,
    float* __restrict__ out) {
  __shared__ __align__(16) float smem[SMEMF];
  const int tid = threadIdx.x;
  const int blk = blockIdx.x;
  const int n = blk & 63;         // image  (XCD colocation: n, n+64, n+128,
  const int g = blk >> 6;         //  n+192 share blk%8)
  const int lane = tid & 63;
  const int wid = tid >> 6;       // wave index (9 waves)
  const int q = lane >> 4;        // ci quadrant (3 = dead)
  const int pl = lane & 15;
  const int ylane = ((q < 3) ? q : 2) * 16 + pl;  // q=3 dupes q=2: broadcast
  // wave->row perm: SIMD (wid&3) loads balanced to max 10 tap-row units.
  // perm = {0,4,2,3,8,5,6,7,1} (chained selects; no local-array scratch)
  const int oh = (wid == 0) ? 0 : (wid == 1) ? 4 : (wid == 4) ? 8
               : (wid == 8) ? 1 : wid;

  int* __restrict__ cnt = (int*)ws + CNTOFF + n * 64;
  const float lam_n = lam[n];
  const float bcv = b_conv[tid % 3];   // pre-pass bias (used when tid<243)
  const float bct0 = b_ct[0], bct1 = b_ct[1], bct2 = b_ct[2];

  // ---- stage LDS ----
  for (int i = tid; i < SMEMF; i += THREADS) smem[i] = 0.f;
  __syncthreads();
  for (int i = tid; i < 4800; i += THREADS) {
    const int lane_i = i & 63;
    const int tc = i >> 6;            // t*3 + co
    const int t_i = tc / 3;
    const int co_i = tc - 3 * t_i;
    smem[LWG + (t_i * 64 + lane_i) * 4 + co_i] = ws[WGOFF + g * 4800 + i];
  }
  smem[LWCT + tid] = ws[WCTOFF + tid];
  if (tid < 243) smem[LXS + tid] = x[n * 243 + tid];
  __syncthreads();

  // stage-2 ownership: thread t<486 owns elements e = 8t .. 8t+7
  const int idx3 = tid >> 1;
  const int cell = idx3 / 3;
  const int c = idx3 - 3 * cell;
  const int cb = 3 * cell;
  const int plb = (tid & 1) * 8;       // p_local base (0 or 8)

  float t = 1.0f;
#pragma unroll 1
  for (int iter = 0; iter < ITERS; ++iter) {
    // ===== stage 1: partial a over this block's 16 phases; wave = oh ==========
    {
      float acc[27];               // [ow*3 + co]
#pragma unroll
      for (int k = 0; k < 27; ++k) acc[k] = 0.f;

#pragma unroll
      for (int th = 0; th < 5; ++th) {
        const int r = oh + th - 2;          // input row
        if (r >= 0 && r <= 8) {
          float rv2[9];                     // y cols 0..8 (no pad needed)
#pragma unroll
          for (int wc = 0; wc < 9; ++wc)
            rv2[wc] = smem[LY + r * 432 + wc * 48 + ylane];

#pragma unroll
          for (int tw = 0; tw < 5; ++tw) {
            // one ds_read_b128 fetches w0,w1,w2 (+pad) for this (th,tw)
            const float4 wv =
                *(const float4*)&smem[LWG + ((th * 5 + tw) * 64 + lane) * 4];
#pragma unroll
            for (int ow = 0; ow < 9; ++ow) {
              const int col = ow + tw - 2;
              if (col >= 0 && col <= 8) {   // compile-time trim (13% fmacs)
                const float y = rv2[col];
                acc[ow * 3 + 0] += y * wv.x;
                acc[ow * 3 + 1] += y * wv.y;
                acc[ow * 3 + 2] += y * wv.z;
              }
            }
          }
        }
      }

      // ---- reduce: 2 DPP stages -> 4-lane group sums in lanes 4m+3;
      // masked transpose write (16 partials per k, stride 20, conflict-
      // free); lanes<27 sum 16 partials; ONE coalesced atomic store ----
      float s4[27];
#pragma unroll
      for (int k = 0; k < 27; ++k) {
        const float s1 = dpp_add<0x111>(acc[k]);   // row_shr:1
        s4[k] = dpp_add<0x112>(s1);                // row_shr:2 -> 4-group sum
      }
      {
        float* Tw = &smem[LT + wid * 540];
        if ((lane & 3) == 3) {
          const int m = lane >> 2;                 // 0..15
#pragma unroll
          for (int k = 0; k < 27; ++k) Tw[k * 20 + m] = s4[k];
        }
        asm volatile("s_waitcnt lgkmcnt(0)" ::: "memory");
        if (lane < 27) {
          const float4* Tr = (const float4*)&Tw[lane * 20];
          const float4 p0 = Tr[0];
          const float4 p1 = Tr[1];
          const float4 p2 = Tr[2];
          const float4 p3 = Tr[3];
          const float s01 = (p0.x + p0.y) + (p0.z + p0.w);
          const float s23 = (p1.x + p1.y) + (p1.z + p1.w);
          const float s45 = (p2.x + p2.y) + (p2.z + p2.w);
          const float s67 = (p3.x + p3.y) + (p3.z + p3.w);
          const float s = (s01 + s23) + (s45 + s67);
          float* ap = ws + APOFF + ((((iter & 1) * 64 + n) * 4 + g) * 243)
                      + oh * 27 + lane;
          __hip_atomic_store(ap, s, __ATOMIC_RELAXED, __HIP_MEMORY_SCOPE_AGENT);
        }
      }
    }

    // ===== centralized barrier (R17-proven): one spinner, rest at s_barrier ==
    __syncthreads();               // compiler drains vmcnt: Ap stores acked at L3
    if (tid == 0) {
      __hip_atomic_fetch_add(cnt, 1, __ATOMIC_RELAXED, __HIP_MEMORY_SCOPE_AGENT);
      const int target = 4 * (iter + 1);
      while (__hip_atomic_load(cnt, __ATOMIC_RELAXED, __HIP_MEMORY_SCOPE_AGENT)
             < target)
        __builtin_amdgcn_s_sleep(1);
    }
    __syncthreads();

    // ===== pre-pass: a = sum_g Ap + b_conv -> LDS (atomic loads: L3-fresh) ====
    if (tid < 243) {
      const float* ap = ws + APOFF + ((iter & 1) * 64 + n) * 972;
      const float a0 = __hip_atomic_load(ap + tid, __ATOMIC_RELAXED,
                                         __HIP_MEMORY_SCOPE_AGENT);
      const float a1 = __hip_atomic_load(ap + 243 + tid, __ATOMIC_RELAXED,
                                         __HIP_MEMORY_SCOPE_AGENT);
      const float a2 = __hip_atomic_load(ap + 486 + tid, __ATOMIC_RELAXED,
                                         __HIP_MEMORY_SCOPE_AGENT);
      const float a3 = __hip_atomic_load(ap + 729 + tid, __ATOMIC_RELAXED,
                                         __HIP_MEMORY_SCOPE_AGENT);
      smem[LA + tid] = a0 + a1 + a2 + a3 + bcv;
    }
    __syncthreads();

    const float tn = (1.0f + sqrtf(1.0f + 4.0f * t * t)) * 0.5f;
    const float beta = (t - 1.0f) / tn;    // beta_0 = 0
    t = tn;

    // ===== stage 2: 8 consecutive elements per thread; y/y_last as float4;
    // a/x/Wct scalar from LDS (no loop-carried registers added) =====
    const bool lastit = (iter == ITERS - 1);
    if (tid < 486) {
      const float a0 = smem[LA + cb + 0];
      const float a1 = smem[LA + cb + 1];
      const float a2 = smem[LA + cb + 2];
      const float r0 = smem[LXS + cb + 0] - a0;
      const float r1 = smem[LXS + cb + 1] - a1;
      const float r2v = smem[LXS + cb + 2] - a2;
      const float bct = (c == 0) ? bct0 : ((c == 1) ? bct1 : bct2);

      float4* lyv  = (float4*)&smem[LY];
      float4* lylv = (float4*)&smem[LYL];
      const float4 y0 = lyv[2 * tid];
      const float4 y1 = lyv[2 * tid + 1];
      const float yv[8] = {y0.x, y0.y, y0.z, y0.w, y1.x, y1.y, y1.z, y1.w};
      float yn[8];
#pragma unroll
      for (int j = 0; j < 8; ++j) {
        const int p = g * 16 + plb + j;
        const float* wp = &smem[LWCT + (p * 3 + c) * 3];
        const float re = bct + r0 * wp[0] + r1 * wp[1] + r2v * wp[2];
        const float wvv = yv[j] - re;
        yn[j] = fmaxf(wvv - lam_n, 0.f) - fmaxf(-wvv - lam_n, 0.f);
      }

      if (!lastit) {
        const float4 l0 = lylv[2 * tid];
        const float4 l1 = lylv[2 * tid + 1];
        const float ylv[8] = {l0.x, l0.y, l0.z, l0.w, l1.x, l1.y, l1.z, l1.w};
        float4 s0, s1, m0, m1;
        s0.x = yn[0]; s0.y = yn[1]; s0.z = yn[2]; s0.w = yn[3];
        s1.x = yn[4]; s1.y = yn[5]; s1.z = yn[6]; s1.w = yn[7];
        m0.x = yn[0] + beta * (yn[0] - ylv[0]);
        m0.y = yn[1] + beta * (yn[1] - ylv[1]);
        m0.z = yn[2] + beta * (yn[2] - ylv[2]);
        m0.w = yn[3] + beta * (yn[3] - ylv[3]);
        m1.x = yn[4] + beta * (yn[4] - ylv[4]);
        m1.y = yn[5] + beta * (yn[5] - ylv[5]);
        m1.z = yn[6] + beta * (yn[6] - ylv[6]);
        m1.w = yn[7] + beta * (yn[7] - ylv[7]);
        lylv[2 * tid] = s0; lylv[2 * tid + 1] = s1;
        lyv[2 * tid]  = m0; lyv[2 * tid + 1]  = m1;
      } else {
        const int part = (g * 16 + plb) >> 3;   // p>>3 constant over j
        const int qh = cell / 9;
        const int qw = cell - 9 * qh;
        const int ih = 8 * qh + part;
        float* op = out + ((n * 72 + ih) * 72 + 8 * qw) * 3 + c;
#pragma unroll
        for (int j = 0; j < 8; ++j) op[3 * j] = yn[j];
      }
    }
    __syncthreads();
  }
}

extern "C" void kernel_launch(void* const* d_in, const int* in_sizes, int n_in,
                              void* d_out, int out_size, void* d_ws, size_t ws_size,
                              hipStream_t stream) {
  const float* x      = (const float*)d_in[0];
  const float* lam    = (const float*)d_in[1];
  const float* w_conv = (const float*)d_in[2];
  const float* b_conv = (const float*)d_in[3];
  const float* w_ct   = (const float*)d_in[4];
  const float* b_ct   = (const float*)d_in[5];
  float* out = (float*)d_out;
  float* ws  = (float*)d_ws;  // needs ~593 KB (R17 layout, unchanged)

  hipLaunchKernelGGL(k0_init, dim3(80), dim3(256), 0, stream, w_conv, w_ct, ws);
  hipLaunchKernelGGL(fista_split, dim3(256), dim3(THREADS), 0, stream,
                     ws, x, lam, b_conv, b_ct, out);
}